// Round 11
// baseline (380.017 us; speedup 1.0000x reference)
//
#include <hip/hip_runtime.h>
#include <hip/hip_bf16.h>
#include <cstddef>
#include <cstdint>

#define B_  512
#define L_  200
#define D_  256
#define K_  2048
#define BL_ (B_ * L_)

typedef __bf16 bf16x8 __attribute__((ext_vector_type(8)));
typedef float  f32x16 __attribute__((ext_vector_type(16)));

#define GL_LDS(g, l) __builtin_amdgcn_global_load_lds(                          \
    (const __attribute__((address_space(1))) void*)(g),                         \
    (__attribute__((address_space(3))) void*)(l), 16, 0, 0)

__device__ inline ushort f2bf(float f) {   // RNE float->bf16 (no NaN in data)
    union { float f; uint u; } a; a.f = f;
    uint r = a.u + 0x7FFFu + ((a.u >> 16) & 1u);
    return (ushort)(r >> 16);
}

// ---------------------------------------------------------------------------
// prep: cnorm[k] = ||c_k||^2 ; cnormR = acc-layout cnorm + 16 (positive-score
// bias; |2 e.c| <= 12 for this data); bf16 row-major codebook copy.
// acc row r = 4h + (j&3) + 8*(j>>2)  ->  cnormR[chunkbase + h*16 + j]
// ---------------------------------------------------------------------------
__global__ __launch_bounds__(256) void prep_kernel(const float* __restrict__ cb,
                                                   float* __restrict__ cnorm,
                                                   float* __restrict__ cnormR,
                                                   ushort* __restrict__ cbbf) {
    int code = (blockIdx.x * 256 + threadIdx.x) >> 6;
    int lane = threadIdx.x & 63;
    float4 v = ((const float4*)(cb + (size_t)code * D_))[lane];
    float s = v.x * v.x + v.y * v.y + v.z * v.z + v.w * v.w;
    #pragma unroll
    for (int off = 32; off; off >>= 1) s += __shfl_down(s, off);
    union { ushort us[4]; uint2 u2; } pk;
    pk.us[0] = f2bf(v.x); pk.us[1] = f2bf(v.y); pk.us[2] = f2bf(v.z); pk.us[3] = f2bf(v.w);
    ((uint2*)(cbbf + (size_t)code * D_))[lane] = pk.u2;
    if (lane == 0) {
        cnorm[code] = s;
        int r = code & 31;
        int h = (r >> 2) & 1;
        int j = (r & 3) | ((r >> 3) << 2);
        cnormR[(code & ~31) | (h << 4) | j] = s + 16.0f;
    }
}

// ---------------------------------------------------------------------------
// gemm_top2 (R7 known-good, 161 us): K-split x2 — block = (pos_tile,
// code_half); 2 waves x 64 pos; 1024 codes/block in 32 chunks of 32 (16 KB
// LDS dbuf, 1 barrier/chunk). acc init = cnormR (+16) -> acc == positive
// score; packed uint keys (score[31:11] | code[10:0]), sorted-pair merge.
// ---------------------------------------------------------------------------
struct CN4 { float4 a, b, c, d; };

__device__ inline CN4 ldcn(const float* p) {
    CN4 r;
    r.a = ((const float4*)p)[0];
    r.b = ((const float4*)p)[1];
    r.c = ((const float4*)p)[2];
    r.d = ((const float4*)p)[3];
    return r;
}

#define STAGE(CIDX, BUF) {                                                      \
    int wub = __builtin_amdgcn_readfirstlane((t >> 6) * 512);                   \
    _Pragma("unroll")                                                           \
    for (int i_ = 0; i_ < 8; ++i_) {                                            \
      int slot = wub + i_ * 64 + (t & 63);                                      \
      int n_ = slot >> 5, up_ = slot & 31;                                      \
      int u_ = up_ ^ (n_ & 7);                                                  \
      GL_LDS(cbbf + (((size_t)((cu << 10) + ((CIDX) << 5) + n_)) << 8) + (u_ << 3), \
             (char*)(BUF) + (size_t)(wub + i_ * 64) * 16);                      \
    } }

#define PROCSEL(BUF, NC, CN) {                                                  \
    f32x16 A0, A1;                                                              \
    A0[0]=(CN).a.x; A0[1]=(CN).a.y; A0[2]=(CN).a.z; A0[3]=(CN).a.w;             \
    A0[4]=(CN).b.x; A0[5]=(CN).b.y; A0[6]=(CN).b.z; A0[7]=(CN).b.w;             \
    A0[8]=(CN).c.x; A0[9]=(CN).c.y; A0[10]=(CN).c.z; A0[11]=(CN).c.w;           \
    A0[12]=(CN).d.x; A0[13]=(CN).d.y; A0[14]=(CN).d.z; A0[15]=(CN).d.w;         \
    A1 = A0;                                                                    \
    _Pragma("unroll")                                                           \
    for (int s_ = 0; s_ < 16; ++s_) {                                           \
      bf16x8 aF = *(const bf16x8*)((const char*)(BUF) +                         \
                    (((l31 << 5) + ((2 * s_ + h) ^ swz)) << 4));                \
      A0 = __builtin_amdgcn_mfma_f32_32x32x16_bf16(aF, bfrag[0][s_], A0, 0,0,0);\
      A1 = __builtin_amdgcn_mfma_f32_32x32x16_bf16(aF, bfrag[1][s_], A1, 0,0,0);\
    }                                                                           \
    uint sb_ = (uint)((cu << 10) + ((NC) << 5));                                \
    _Pragma("unroll")                                                           \
    for (int jp_ = 0; jp_ < 8; ++jp_) {                                         \
      int j0_ = 2 * jp_, j1_ = 2 * jp_ + 1;                                     \
      uint c0_ = sb_ + (uint)((j0_ & 3) + 8 * (j0_ >> 2));                      \
      uint c1_ = sb_ + (uint)((j1_ & 3) + 8 * (j1_ >> 2));                      \
      {                                                                         \
        uint ka = (__float_as_uint(A0[j0_]) & 0xFFFFF800u) | (c0_ + h4);        \
        uint kb = (__float_as_uint(A0[j1_]) & 0xFFFFF800u) | (c1_ + h4);        \
        uint lo = min(ka, kb), hi = max(ka, kb);                                \
        uint tt = max(b1a, lo);                                                 \
        b1a = min(b1a, lo);                                                     \
        b2a = min(min(b2a, tt), hi);                                            \
      }                                                                         \
      {                                                                         \
        uint ka = (__float_as_uint(A1[j0_]) & 0xFFFFF800u) | (c0_ + h4);        \
        uint kb = (__float_as_uint(A1[j1_]) & 0xFFFFF800u) | (c1_ + h4);        \
        uint lo = min(ka, kb), hi = max(ka, kb);                                \
        uint tt = max(b1b, lo);                                                 \
        b1b = min(b1b, lo);                                                     \
        b2b = min(min(b2b, tt), hi);                                            \
      }                                                                         \
    } }

__global__ __launch_bounds__(128, 2) void gemm_top2_kernel(
    const int* __restrict__ ids, const int* __restrict__ masks,
    const float* __restrict__ table, const ushort* __restrict__ cbbf,
    const float* __restrict__ cnormR, uint2* __restrict__ cand) {

  __shared__ ushort cbuf0[32 * 256];   // 16 KB
  __shared__ ushort cbuf1[32 * 256];   // 16 KB

  const int t    = threadIdx.x;
  const int lane = t & 63;
  const int l31  = lane & 31;
  const int h    = lane >> 5;
  const int w    = t >> 6;
  const int ptile = blockIdx.x >> 1;
  const int cu    = blockIdx.x & 1;
  const int swz  = l31 & 7;
  const uint h4  = (uint)(h << 2);

  // ---- B-frags: -2 * masked embeddings, position-stationary in registers ----
  bf16x8 bfrag[2][16];
  #pragma unroll
  for (int pt = 0; pt < 2; ++pt) {
    int pos = ptile * 128 + w * 64 + pt * 32 + l31;
    int id  = ids[pos];
    float m = (masks[pos] >= 1) ? -2.0f : 0.0f;
    const float* er = table + (size_t)id * D_ + 8 * h;
    #pragma unroll
    for (int s = 0; s < 16; ++s) {
      float4 x = *(const float4*)(er + 16 * s);
      float4 y = *(const float4*)(er + 16 * s + 4);
      bf16x8 b;
      b[0] = (__bf16)(x.x * m); b[1] = (__bf16)(x.y * m);
      b[2] = (__bf16)(x.z * m); b[3] = (__bf16)(x.w * m);
      b[4] = (__bf16)(y.x * m); b[5] = (__bf16)(y.y * m);
      b[6] = (__bf16)(y.z * m); b[7] = (__bf16)(y.w * m);
      bfrag[pt][s] = b;
    }
  }

  uint b1a = 0xFFFFFFFFu, b2a = 0xFFFFFFFFu;
  uint b1b = 0xFFFFFFFFu, b2b = 0xFFFFFFFFu;

  const float* cnh = cnormR + (cu << 10);
  CN4 cnA = ldcn(cnh + 0 * 32 + h * 16);
  STAGE(0, cbuf0);
  __syncthreads();

  #pragma unroll 1
  for (int nc = 0; nc < 32; nc += 2) {
    CN4 cnB = ldcn(cnh + (nc + 1) * 32 + h * 16);
    STAGE(nc + 1, cbuf1);
    PROCSEL(cbuf0, nc, cnA);
    __syncthreads();
    if (nc + 2 < 32) {
      cnA = ldcn(cnh + (nc + 2) * 32 + h * 16);
      STAGE(nc + 2, cbuf0);
    }
    PROCSEL(cbuf1, nc + 1, cnB);
    __syncthreads();
  }

  // ---- merge h=0/h=1 partner lanes (disjoint code rows, same position) ----
  {
    uint ob1 = __shfl_xor(b1a, 32), ob2 = __shfl_xor(b2a, 32);
    uint m1 = min(b1a, ob1);
    uint m2 = min(min(max(b1a, ob1), b2a), ob2);
    if (h == 0) cand[(size_t)(ptile * 128 + w * 64 + 0 * 32 + l31) * 2 + cu] = make_uint2(m1, m2);
  }
  {
    uint ob1 = __shfl_xor(b1b, 32), ob2 = __shfl_xor(b2b, 32);
    uint m1 = min(b1b, ob1);
    uint m2 = min(min(max(b1b, ob1), b2b), ob2);
    if (h == 0) cand[(size_t)(ptile * 128 + w * 64 + 1 * 32 + l31) * 2 + cu] = make_uint2(m1, m2);
  }
}

// ---------------------------------------------------------------------------
// tail: ONE kernel, one block per batch (4 waves). Each wave rescores 50
// positions in groups of 5 (15 gather chains in flight), accumulates vq/e
// sums in registers; LDS cross-wave reduce; means + GEMV in the same block.
// No global accumulators, no memset, no separate dense kernel.
// ---------------------------------------------------------------------------
#define GRP 5

__global__ __launch_bounds__(256, 2) void tail_kernel(
    const int* __restrict__ ids, const int* __restrict__ masks,
    const float* __restrict__ table, const float* __restrict__ cb,
    const float* __restrict__ cnorm, const uint4* __restrict__ cand4,
    const float* __restrict__ W, const float* __restrict__ bvec,
    float* __restrict__ out) {

    __shared__ float red_vq[4][D_];   // 4 KB
    __shared__ float red_e[4][D_];    // 4 KB
    __shared__ float x[2 * D_];       // 2 KB
    __shared__ int   redc[4];

    const int b = blockIdx.x;
    const int t = threadIdx.x;
    const int wv = t >> 6, lane = t & 63;

    float4 vqa = make_float4(0.f, 0.f, 0.f, 0.f);
    float4 ea  = make_float4(0.f, 0.f, 0.f, 0.f);
    int cnta = 0;

    #pragma unroll 1
    for (int g = 0; g < 50 / GRP; ++g) {
        const int l0 = wv * 50 + g * GRP;

        float4 e[GRP], c1[GRP], c2[GRP];
        int k1[GRP], k2[GRP];
        float mm[GRP];
        #pragma unroll
        for (int j = 0; j < GRP; ++j) {
            int u = b * L_ + l0 + j;
            uint4 k4 = cand4[u];
            uint g1 = min(k4.x, k4.z);
            uint g2 = min(min(max(k4.x, k4.z), k4.y), k4.w);
            k1[j] = (int)(g1 & 0x7FFu);
            k2[j] = (int)(g2 & 0x7FFu);
            int id = ids[u];
            mm[j] = (masks[u] >= 1) ? 1.0f : 0.0f;
            e[j]  = ((const float4*)(table + (size_t)id * D_))[lane];
            c1[j] = ((const float4*)(cb + (size_t)k1[j] * D_))[lane];
            c2[j] = ((const float4*)(cb + (size_t)k2[j] * D_))[lane];
        }

        float d1[GRP], d2[GRP];
        #pragma unroll
        for (int j = 0; j < GRP; ++j) {
            d1[j] = fmaf(e[j].x, c1[j].x, fmaf(e[j].y, c1[j].y,
                     fmaf(e[j].z, c1[j].z, e[j].w * c1[j].w)));
            d2[j] = fmaf(e[j].x, c2[j].x, fmaf(e[j].y, c2[j].y,
                     fmaf(e[j].z, c2[j].z, e[j].w * c2[j].w)));
        }
        #pragma unroll
        for (int off = 32; off; off >>= 1) {
            #pragma unroll
            for (int j = 0; j < GRP; ++j) {
                d1[j] += __shfl_xor(d1[j], off);
                d2[j] += __shfl_xor(d2[j], off);
            }
        }
        #pragma unroll
        for (int j = 0; j < GRP; ++j) {
            float s1 = cnorm[k1[j]] - 2.0f * mm[j] * d1[j];
            float s2 = cnorm[k2[j]] - 2.0f * mm[j] * d2[j];
            bool sel = (s2 < s1) || (s2 == s1 && k2[j] < k1[j]);  // first-min
            float4 ch = sel ? c2[j] : c1[j];
            vqa.x += ch.x; vqa.y += ch.y; vqa.z += ch.z; vqa.w += ch.w;
            ea.x = fmaf(mm[j], e[j].x, ea.x);
            ea.y = fmaf(mm[j], e[j].y, ea.y);
            ea.z = fmaf(mm[j], e[j].z, ea.z);
            ea.w = fmaf(mm[j], e[j].w, ea.w);
            cnta += (mm[j] != 0.f) ? 1 : 0;
        }
    }

    *(float4*)&red_vq[wv][lane * 4] = vqa;
    *(float4*)&red_e[wv][lane * 4]  = ea;
    if (lane == 0) redc[wv] = cnta;
    __syncthreads();

    // means (t = dim 0..255)
    {
        float fc = (float)(redc[0] + redc[1] + redc[2] + redc[3]);
        float vs = red_vq[0][t] + red_vq[1][t] + red_vq[2][t] + red_vq[3][t];
        float es = red_e[0][t] + red_e[1][t] + red_e[2][t] + red_e[3][t];
        x[t]      = vs / fc;             // vq_mean (no eps)
        x[D_ + t] = es / (fc + 1e-9f);   // hist_mean (+1e-9)
    }
    __syncthreads();

    // GEMV: out[b][t] = bvec[t] + sum_i x[i] * W[i][t]
    float acc = bvec[t];
    #pragma unroll 8
    for (int i = 0; i < 2 * D_; ++i)
        acc = fmaf(x[i], W[i * D_ + t], acc);
    out[(size_t)b * D_ + t] = acc;
}

// ---------------------------------------------------------------------------
extern "C" void kernel_launch(void* const* d_in, const int* in_sizes, int n_in,
                              void* d_out, int out_size, void* d_ws, size_t ws_size,
                              hipStream_t stream) {
    const int*   ids   = (const int*)  d_in[0];
    const int*   masks = (const int*)  d_in[1];
    const float* table = (const float*)d_in[2];
    const float* cb    = (const float*)d_in[3];
    const float* W     = (const float*)d_in[4];
    const float* bvec  = (const float*)d_in[5];
    float* out = (float*)d_out;

    char* p = (char*)d_ws;
    float*  cnorm  = (float*)p;             p += 8192;                  // 8 KB
    float*  cnormR = (float*)p;             p += 8192;                  // 8 KB
    ushort* cbbf   = (ushort*)p;            p += 1048576;               // 1 MB
    uint2*  cand   = (uint2*)p;             p += (size_t)BL_ * 16;      // 1.6 MB

    prep_kernel<<<K_ * 64 / 256, 256, 0, stream>>>(cb, cnorm, cnormR, cbbf);
    gemm_top2_kernel<<<(BL_ / 128) * 2, 128, 0, stream>>>(ids, masks, table, cbbf, cnormR, cand);
    tail_kernel<<<B_, 256, 0, stream>>>(ids, masks, table, cb, cnorm,
                                        (const uint4*)cand, W, bvec, out);
}

// Round 12
// 332.710 us; speedup vs baseline: 1.1422x; 1.1422x over previous
//
#include <hip/hip_runtime.h>
#include <hip/hip_bf16.h>
#include <cstddef>
#include <cstdint>

#define B_  512
#define L_  200
#define D_  256
#define K_  2048
#define BL_ (B_ * L_)

typedef __bf16 bf16x8 __attribute__((ext_vector_type(8)));
typedef float  f32x16 __attribute__((ext_vector_type(16)));

#define GL_LDS(g, l) __builtin_amdgcn_global_load_lds(                          \
    (const __attribute__((address_space(1))) void*)(g),                         \
    (__attribute__((address_space(3))) void*)(l), 16, 0, 0)

__device__ inline ushort f2bf(float f) {   // RNE float->bf16 (no NaN in data)
    union { float f; uint u; } a; a.f = f;
    uint r = a.u + 0x7FFFu + ((a.u >> 16) & 1u);
    return (ushort)(r >> 16);
}

// ---------------------------------------------------------------------------
// prep: cnorm[k] = ||c_k||^2 ; cnormR = acc-layout cnorm + 16 (positive-score
// bias; |2 e.c| <= 12 for this data); bf16 row-major codebook copy.
// ---------------------------------------------------------------------------
__global__ __launch_bounds__(256) void prep_kernel(const float* __restrict__ cb,
                                                   float* __restrict__ cnorm,
                                                   float* __restrict__ cnormR,
                                                   ushort* __restrict__ cbbf) {
    int code = (blockIdx.x * 256 + threadIdx.x) >> 6;
    int lane = threadIdx.x & 63;
    float4 v = ((const float4*)(cb + (size_t)code * D_))[lane];
    float s = v.x * v.x + v.y * v.y + v.z * v.z + v.w * v.w;
    #pragma unroll
    for (int off = 32; off; off >>= 1) s += __shfl_down(s, off);
    union { ushort us[4]; uint2 u2; } pk;
    pk.us[0] = f2bf(v.x); pk.us[1] = f2bf(v.y); pk.us[2] = f2bf(v.z); pk.us[3] = f2bf(v.w);
    ((uint2*)(cbbf + (size_t)code * D_))[lane] = pk.u2;
    if (lane == 0) {
        cnorm[code] = s;
        int r = code & 31;
        int h = (r >> 2) & 1;
        int j = (r & 3) | ((r >> 3) << 2);
        cnormR[(code & ~31) | (h << 4) | j] = s + 16.0f;
    }
}

// ---------------------------------------------------------------------------
// kstar: argmin_k cnorm[k] with lowest-idx tie-break (exact). One block.
// ---------------------------------------------------------------------------
__global__ __launch_bounds__(256) void kstar_kernel(const float* __restrict__ cnorm,
                                                    int* __restrict__ kstar) {
    __shared__ unsigned long long red[4];
    const int t = threadIdx.x;
    unsigned long long best = ~0ull;
    #pragma unroll
    for (int i = 0; i < K_ / 256; ++i) {
        int k = i * 256 + t;
        unsigned long long key = (((unsigned long long)__float_as_uint(cnorm[k])) << 11) | (unsigned)k;
        best = best < key ? best : key;
    }
    #pragma unroll
    for (int off = 32; off; off >>= 1) {
        unsigned long long o = __shfl_down(best, off);
        best = best < o ? best : o;
    }
    if ((t & 63) == 0) red[t >> 6] = best;
    __syncthreads();
    if (t == 0) {
        unsigned long long b = red[0];
        for (int i = 1; i < 4; ++i) b = b < red[i] ? b : red[i];
        kstar[0] = (int)(b & 0x7FFull);
    }
}

// ---------------------------------------------------------------------------
// gemm_top2 (R7 known-good, 161 us) — unchanged.
// ---------------------------------------------------------------------------
struct CN4 { float4 a, b, c, d; };

__device__ inline CN4 ldcn(const float* p) {
    CN4 r;
    r.a = ((const float4*)p)[0];
    r.b = ((const float4*)p)[1];
    r.c = ((const float4*)p)[2];
    r.d = ((const float4*)p)[3];
    return r;
}

#define STAGE(CIDX, BUF) {                                                      \
    int wub = __builtin_amdgcn_readfirstlane((t >> 6) * 512);                   \
    _Pragma("unroll")                                                           \
    for (int i_ = 0; i_ < 8; ++i_) {                                            \
      int slot = wub + i_ * 64 + (t & 63);                                      \
      int n_ = slot >> 5, up_ = slot & 31;                                      \
      int u_ = up_ ^ (n_ & 7);                                                  \
      GL_LDS(cbbf + (((size_t)((cu << 10) + ((CIDX) << 5) + n_)) << 8) + (u_ << 3), \
             (char*)(BUF) + (size_t)(wub + i_ * 64) * 16);                      \
    } }

#define PROCSEL(BUF, NC, CN) {                                                  \
    f32x16 A0, A1;                                                              \
    A0[0]=(CN).a.x; A0[1]=(CN).a.y; A0[2]=(CN).a.z; A0[3]=(CN).a.w;             \
    A0[4]=(CN).b.x; A0[5]=(CN).b.y; A0[6]=(CN).b.z; A0[7]=(CN).b.w;             \
    A0[8]=(CN).c.x; A0[9]=(CN).c.y; A0[10]=(CN).c.z; A0[11]=(CN).c.w;           \
    A0[12]=(CN).d.x; A0[13]=(CN).d.y; A0[14]=(CN).d.z; A0[15]=(CN).d.w;         \
    A1 = A0;                                                                    \
    _Pragma("unroll")                                                           \
    for (int s_ = 0; s_ < 16; ++s_) {                                           \
      bf16x8 aF = *(const bf16x8*)((const char*)(BUF) +                         \
                    (((l31 << 5) + ((2 * s_ + h) ^ swz)) << 4));                \
      A0 = __builtin_amdgcn_mfma_f32_32x32x16_bf16(aF, bfrag[0][s_], A0, 0,0,0);\
      A1 = __builtin_amdgcn_mfma_f32_32x32x16_bf16(aF, bfrag[1][s_], A1, 0,0,0);\
    }                                                                           \
    uint sb_ = (uint)((cu << 10) + ((NC) << 5));                                \
    _Pragma("unroll")                                                           \
    for (int jp_ = 0; jp_ < 8; ++jp_) {                                         \
      int j0_ = 2 * jp_, j1_ = 2 * jp_ + 1;                                     \
      uint c0_ = sb_ + (uint)((j0_ & 3) + 8 * (j0_ >> 2));                      \
      uint c1_ = sb_ + (uint)((j1_ & 3) + 8 * (j1_ >> 2));                      \
      {                                                                         \
        uint ka = (__float_as_uint(A0[j0_]) & 0xFFFFF800u) | (c0_ + h4);        \
        uint kb = (__float_as_uint(A0[j1_]) & 0xFFFFF800u) | (c1_ + h4);        \
        uint lo = min(ka, kb), hi = max(ka, kb);                                \
        uint tt = max(b1a, lo);                                                 \
        b1a = min(b1a, lo);                                                     \
        b2a = min(min(b2a, tt), hi);                                            \
      }                                                                         \
      {                                                                         \
        uint ka = (__float_as_uint(A1[j0_]) & 0xFFFFF800u) | (c0_ + h4);        \
        uint kb = (__float_as_uint(A1[j1_]) & 0xFFFFF800u) | (c1_ + h4);        \
        uint lo = min(ka, kb), hi = max(ka, kb);                                \
        uint tt = max(b1b, lo);                                                 \
        b1b = min(b1b, lo);                                                     \
        b2b = min(min(b2b, tt), hi);                                            \
      }                                                                         \
    } }

__global__ __launch_bounds__(128, 2) void gemm_top2_kernel(
    const int* __restrict__ ids, const int* __restrict__ masks,
    const float* __restrict__ table, const ushort* __restrict__ cbbf,
    const float* __restrict__ cnormR, uint2* __restrict__ cand) {

  __shared__ ushort cbuf0[32 * 256];   // 16 KB
  __shared__ ushort cbuf1[32 * 256];   // 16 KB

  const int t    = threadIdx.x;
  const int lane = t & 63;
  const int l31  = lane & 31;
  const int h    = lane >> 5;
  const int w    = t >> 6;
  const int ptile = blockIdx.x >> 1;
  const int cu    = blockIdx.x & 1;
  const int swz  = l31 & 7;
  const uint h4  = (uint)(h << 2);

  bf16x8 bfrag[2][16];
  #pragma unroll
  for (int pt = 0; pt < 2; ++pt) {
    int pos = ptile * 128 + w * 64 + pt * 32 + l31;
    int id  = ids[pos];
    float m = (masks[pos] >= 1) ? -2.0f : 0.0f;
    const float* er = table + (size_t)id * D_ + 8 * h;
    #pragma unroll
    for (int s = 0; s < 16; ++s) {
      float4 x = *(const float4*)(er + 16 * s);
      float4 y = *(const float4*)(er + 16 * s + 4);
      bf16x8 b;
      b[0] = (__bf16)(x.x * m); b[1] = (__bf16)(x.y * m);
      b[2] = (__bf16)(x.z * m); b[3] = (__bf16)(x.w * m);
      b[4] = (__bf16)(y.x * m); b[5] = (__bf16)(y.y * m);
      b[6] = (__bf16)(y.z * m); b[7] = (__bf16)(y.w * m);
      bfrag[pt][s] = b;
    }
  }

  uint b1a = 0xFFFFFFFFu, b2a = 0xFFFFFFFFu;
  uint b1b = 0xFFFFFFFFu, b2b = 0xFFFFFFFFu;

  const float* cnh = cnormR + (cu << 10);
  CN4 cnA = ldcn(cnh + 0 * 32 + h * 16);
  STAGE(0, cbuf0);
  __syncthreads();

  #pragma unroll 1
  for (int nc = 0; nc < 32; nc += 2) {
    CN4 cnB = ldcn(cnh + (nc + 1) * 32 + h * 16);
    STAGE(nc + 1, cbuf1);
    PROCSEL(cbuf0, nc, cnA);
    __syncthreads();
    if (nc + 2 < 32) {
      cnA = ldcn(cnh + (nc + 2) * 32 + h * 16);
      STAGE(nc + 2, cbuf0);
    }
    PROCSEL(cbuf1, nc + 1, cnB);
    __syncthreads();
  }

  {
    uint ob1 = __shfl_xor(b1a, 32), ob2 = __shfl_xor(b2a, 32);
    uint m1 = min(b1a, ob1);
    uint m2 = min(min(max(b1a, ob1), b2a), ob2);
    if (h == 0) cand[(size_t)(ptile * 128 + w * 64 + 0 * 32 + l31) * 2 + cu] = make_uint2(m1, m2);
  }
  {
    uint ob1 = __shfl_xor(b1b, 32), ob2 = __shfl_xor(b2b, 32);
    uint m1 = min(b1b, ob1);
    uint m2 = min(min(max(b1b, ob1), b2b), ob2);
    if (h == 0) cand[(size_t)(ptile * 128 + w * 64 + 1 * 32 + l31) * 2 + cu] = make_uint2(m1, m2);
  }
}

// ---------------------------------------------------------------------------
// tail: 2 blocks/batch, 4 waves, 25 pos/wave in groups of 5. Masked
// positions: skip all gathers (contribute c_{k*}). Margin filter: keys
// differing by >= 3 granules (>>11) need no exact rescore. Needy (~10-20%):
// gather c2, exact fp32 dots + shfl. Register accumulation -> LDS reduce ->
// global atomicAdd into gacc/gcnt.
// ---------------------------------------------------------------------------
#define GRP 5

__global__ __launch_bounds__(256, 1) void tail_kernel(
    const int* __restrict__ ids, const int* __restrict__ masks,
    const float* __restrict__ table, const float* __restrict__ cb,
    const float* __restrict__ cnorm, const uint4* __restrict__ cand4,
    const int* __restrict__ kstar,
    float* __restrict__ gacc, int* __restrict__ gcnt) {

    __shared__ float red_vq[4][D_];   // 4 KB
    __shared__ float red_e[4][D_];    // 4 KB
    __shared__ int   redc[4];

    const int b    = blockIdx.x >> 1;
    const int half = blockIdx.x & 1;
    const int t = threadIdx.x;
    const int wv = t >> 6, lane = t & 63;

    const int ks = kstar[0];
    float4 ckstar = ((const float4*)(cb + (size_t)ks * D_))[lane];

    float4 vqa = make_float4(0.f, 0.f, 0.f, 0.f);
    float4 ea  = make_float4(0.f, 0.f, 0.f, 0.f);
    int cnta = 0, mcnt = 0;

    #pragma unroll 1
    for (int g = 0; g < 25 / GRP; ++g) {
        const int l0 = half * 100 + wv * 25 + g * GRP;

        uint4 k4[GRP];
        int   id[GRP];
        int   mk[GRP];
        #pragma unroll
        for (int j = 0; j < GRP; ++j) {
            int u = b * L_ + l0 + j;
            k4[j] = cand4[u];
            id[j] = ids[u];
            mk[j] = masks[u];
        }

        int k1[GRP], k2[GRP];
        bool valid[GRP], needy[GRP];
        #pragma unroll
        for (int j = 0; j < GRP; ++j) {
            uint g1 = min(k4[j].x, k4[j].z);
            uint g2 = min(min(max(k4[j].x, k4[j].z), k4[j].y), k4[j].w);
            k1[j] = (int)(g1 & 0x7FFu);
            k2[j] = (int)(g2 & 0x7FFu);
            valid[j] = (mk[j] >= 1);
            needy[j] = valid[j] && (((g2 & 0xFFFFF800u) - (g1 & 0xFFFFF800u)) < (3u << 11));
        }

        // issue all row gathers (independent; wave-uniform branches)
        float4 e[GRP], c1[GRP], c2[GRP];
        #pragma unroll
        for (int j = 0; j < GRP; ++j)
            if (valid[j]) e[j] = ((const float4*)(table + (size_t)id[j] * D_))[lane];
        #pragma unroll
        for (int j = 0; j < GRP; ++j)
            if (valid[j]) c1[j] = ((const float4*)(cb + (size_t)k1[j] * D_))[lane];
        #pragma unroll
        for (int j = 0; j < GRP; ++j)
            if (needy[j]) c2[j] = ((const float4*)(cb + (size_t)k2[j] * D_))[lane];

        #pragma unroll
        for (int j = 0; j < GRP; ++j) {
            if (!valid[j]) { mcnt++; continue; }
            float4 ch = c1[j];
            if (needy[j]) {
                float d1 = fmaf(e[j].x, c1[j].x, fmaf(e[j].y, c1[j].y,
                            fmaf(e[j].z, c1[j].z, e[j].w * c1[j].w)));
                float d2 = fmaf(e[j].x, c2[j].x, fmaf(e[j].y, c2[j].y,
                            fmaf(e[j].z, c2[j].z, e[j].w * c2[j].w)));
                #pragma unroll
                for (int off = 32; off; off >>= 1) {
                    d1 += __shfl_xor(d1, off);
                    d2 += __shfl_xor(d2, off);
                }
                float s1 = cnorm[k1[j]] - 2.0f * d1;
                float s2 = cnorm[k2[j]] - 2.0f * d2;
                bool sel = (s2 < s1) || (s2 == s1 && k2[j] < k1[j]);  // first-min
                ch = sel ? c2[j] : c1[j];
            }
            vqa.x += ch.x; vqa.y += ch.y; vqa.z += ch.z; vqa.w += ch.w;
            ea.x += e[j].x; ea.y += e[j].y; ea.z += e[j].z; ea.w += e[j].w;
            cnta++;
        }
    }

    // masked positions all choose c_{k*}
    float fm = (float)mcnt;
    vqa.x = fmaf(fm, ckstar.x, vqa.x);
    vqa.y = fmaf(fm, ckstar.y, vqa.y);
    vqa.z = fmaf(fm, ckstar.z, vqa.z);
    vqa.w = fmaf(fm, ckstar.w, vqa.w);

    *(float4*)&red_vq[wv][lane * 4] = vqa;
    *(float4*)&red_e[wv][lane * 4]  = ea;
    if (lane == 0) redc[wv] = cnta;
    __syncthreads();

    float vs = red_vq[0][t] + red_vq[1][t] + red_vq[2][t] + red_vq[3][t];
    float es = red_e[0][t] + red_e[1][t] + red_e[2][t] + red_e[3][t];
    atomicAdd(&gacc[(size_t)b * (2 * D_) + t], vs);
    atomicAdd(&gacc[(size_t)b * (2 * D_) + D_ + t], es);
    if (t == 0) atomicAdd(&gcnt[b], redc[0] + redc[1] + redc[2] + redc[3]);
}

// ---------------------------------------------------------------------------
// dense: per-batch means + concat + GEMV.
// ---------------------------------------------------------------------------
__global__ __launch_bounds__(256) void dense_kernel(
    const float* __restrict__ gacc, const int* __restrict__ gcnt,
    const float* __restrict__ W, const float* __restrict__ bvec,
    float* __restrict__ out) {

    __shared__ float x[2 * D_];
    const int b = blockIdx.x;
    const int t = threadIdx.x;

    float fc = (float)gcnt[b];
    x[t]      = gacc[(size_t)b * (2 * D_) + t] / fc;                // vq_mean (no eps)
    x[D_ + t] = gacc[(size_t)b * (2 * D_) + D_ + t] / (fc + 1e-9f); // hist_mean
    __syncthreads();

    float acc = bvec[t];
    #pragma unroll 8
    for (int i = 0; i < 2 * D_; ++i)
        acc = fmaf(x[i], W[i * D_ + t], acc);
    out[(size_t)b * D_ + t] = acc;
}

// ---------------------------------------------------------------------------
extern "C" void kernel_launch(void* const* d_in, const int* in_sizes, int n_in,
                              void* d_out, int out_size, void* d_ws, size_t ws_size,
                              hipStream_t stream) {
    const int*   ids   = (const int*)  d_in[0];
    const int*   masks = (const int*)  d_in[1];
    const float* table = (const float*)d_in[2];
    const float* cb    = (const float*)d_in[3];
    const float* W     = (const float*)d_in[4];
    const float* bvec  = (const float*)d_in[5];
    float* out = (float*)d_out;

    char* p = (char*)d_ws;
    float*  cnorm  = (float*)p;             p += 8192;                  // 8 KB
    float*  cnormR = (float*)p;             p += 8192;                  // 8 KB
    ushort* cbbf   = (ushort*)p;            p += 1048576;               // 1 MB
    uint2*  cand   = (uint2*)p;             p += (size_t)BL_ * 16;      // 1.6 MB
    float*  gacc   = (float*)p;             p += (size_t)B_ * 2 * D_ * 4; // 1 MB
    int*    gcnt   = (int*)p;               p += B_ * 4;                // 2 KB
    int*    kstar  = (int*)p;               p += 64;

    hipMemsetAsync(gacc, 0, (size_t)B_ * 2 * D_ * 4 + B_ * 4, stream);

    prep_kernel<<<K_ * 64 / 256, 256, 0, stream>>>(cb, cnorm, cnormR, cbbf);
    kstar_kernel<<<1, 256, 0, stream>>>(cnorm, kstar);
    gemm_top2_kernel<<<(BL_ / 128) * 2, 128, 0, stream>>>(ids, masks, table, cbbf, cnormR, cand);
    tail_kernel<<<B_ * 2, 256, 0, stream>>>(ids, masks, table, cb, cnorm,
                                            (const uint4*)cand, kstar, gacc, gcnt);
    dense_kernel<<<B_, 256, 0, stream>>>(gacc, gcnt, W, bvec, out);
}